// Round 7
// baseline (1411.937 us; speedup 1.0000x reference)
//
#include <hip/hip_runtime.h>
#include <stdint.h>

// W8A16 GEMM: out[m,n] = s[n] * sum_k a[m,k] * q_int8[k,n] + bias[n]
// M=8192, N=16384, K=4096. Harness dtypes: A,S,Bias f32; Q int32; OUT f32.
//
// Round 7: 256x256 / BK=64 / 8 waves, 4-phase-per-K-tile interleave
// (ds_read || stage || 16-MFMA per phase, 2 barriers/phase), stage of tile
// t+1 into the slot vacated by tile t-1, one vmcnt(0) per K-tile.

typedef __bf16 bf16x8 __attribute__((ext_vector_type(8)));
typedef float  f32x4  __attribute__((ext_vector_type(4)));

#define M_TOT 8192
#define N_TOT 16384
#define K_TOT 4096
#define BM 256
#define BN 256
#define BK 64
#define NT (K_TOT / BK)        // 64 K-tiles
#define SLOT_ELEMS 16384       // 256 rows * 64 cols bf16 = 32 KB per operand slot

__device__ __forceinline__ void gload_lds16(const void* g, void* l) {
  __builtin_amdgcn_global_load_lds(
      (const __attribute__((address_space(1))) unsigned int*)g,
      (__attribute__((address_space(3))) unsigned int*)l,
      16, 0, 0);
}

// ---------------- pre-pass 1: A f32 -> bf16 ----------------
__global__ void __launch_bounds__(256)
cvt_a_kernel(const float* __restrict__ A, __bf16* __restrict__ Abf) {
  const size_t i = ((size_t)blockIdx.x * 256 + threadIdx.x) * 8;
  f32x4 lo = *(const f32x4*)(A + i);
  f32x4 hi = *(const f32x4*)(A + i + 4);
  bf16x8 v;
  #pragma unroll
  for (int j = 0; j < 4; ++j) {
    v[j]     = (__bf16)lo[j];
    v[j + 4] = (__bf16)hi[j];
  }
  *(bf16x8*)(Abf + i) = v;
}

// ---------------- pre-pass 2: Q [K][N] int32 -> Bt [N][K] bf16 ------------
__global__ void __launch_bounds__(256)
transpose_q_kernel(const int* __restrict__ Q, __bf16* __restrict__ Bt) {
  const int bk = blockIdx.x & 63;        // 64 k-tiles
  const int bn = blockIdx.x >> 6;        // 256 n-tiles
  const int k0 = bk * 64, n0 = bn * 64;
  const int tx = threadIdx.x & 63;       // n within tile
  const int ty = threadIdx.x >> 6;       // k-chunk of 16
  const int kb = k0 + ty * 16;
  const int n  = n0 + tx;
  int q[16];
  #pragma unroll
  for (int i = 0; i < 16; ++i)
    q[i] = Q[(size_t)(kb + i) * N_TOT + n];
  bf16x8 v0, v1;
  #pragma unroll
  for (int i = 0; i < 8; ++i) {
    v0[i] = (__bf16)(float)q[i];
    v1[i] = (__bf16)(float)q[i + 8];
  }
  *(bf16x8*)(Bt + (size_t)n * K_TOT + kb)     = v0;
  *(bf16x8*)(Bt + (size_t)n * K_TOT + kb + 8) = v1;
}

// ---------------- main GEMM: 256^2 / BK=64 / 4-phase interleave ----------
__global__ void __launch_bounds__(512, 2)
w8a16_gemm_ws(const __bf16* __restrict__ A,   // [M,K] bf16
              const __bf16* __restrict__ Bt,  // [N,K] bf16
              const float*  __restrict__ S,
              const float*  __restrict__ Bias,
              float*        __restrict__ O)
{
  extern __shared__ __bf16 lds[];
  __bf16* const aBase0 = lds;                     // A slots [2][16384]
  __bf16* const bBase0 = lds + 2 * SLOT_ELEMS;    // B slots [2][16384]

  const int tid  = threadIdx.x;
  const int lane = tid & 63;
  const int wv   = tid >> 6;     // 0..7
  const int wm   = wv >> 2;      // 0..1 : M-wave (rows wm*128)
  const int wn   = wv & 3;       // 0..3 : N-wave (cols wn*64)

  // XCD map: xcd owns 8 bx-columns; by fastest (B-panel L2-resident).
  const int bid = blockIdx.x;
  const int xcd = bid & 7;
  const int c   = bid >> 3;                 // [0,256)
  const int bx  = xcd * 8 + (c >> 5);       // [0,64)
  const int by  = c & 31;                   // [0,32)
  const int m0  = by * BM;
  const int n0  = bx * BN;

  // ---- staging geometry (identical algebra to R6, verified) ----
  // round j covers rows j*64 + rr; phys chunk = tid&7; logical = phys ^ (rr&7)
  const int rr   = tid >> 3;                       // 0..63
  const int cswz = (tid & 7) ^ (rr & 7);
  const __bf16* pa0 = A  + (size_t)(m0 + 0   + rr) * K_TOT + cswz * 8;
  const __bf16* pa1 = A  + (size_t)(m0 + 64  + rr) * K_TOT + cswz * 8;
  const __bf16* pa2 = A  + (size_t)(m0 + 128 + rr) * K_TOT + cswz * 8;
  const __bf16* pa3 = A  + (size_t)(m0 + 192 + rr) * K_TOT + cswz * 8;
  const __bf16* pb0 = Bt + (size_t)(n0 + 0   + rr) * K_TOT + cswz * 8;
  const __bf16* pb1 = Bt + (size_t)(n0 + 64  + rr) * K_TOT + cswz * 8;
  const __bf16* pb2 = Bt + (size_t)(n0 + 128 + rr) * K_TOT + cswz * 8;
  const __bf16* pb3 = Bt + (size_t)(n0 + 192 + rr) * K_TOT + cswz * 8;
  const int dA = tid * 8;

#define STAGE_A(tt) do { const size_t ko_ = (size_t)(tt) * BK;          \
    gload_lds16(pa0 + ko_, aN + dA);                                    \
    gload_lds16(pa1 + ko_, aN + 4096  + dA);                            \
    gload_lds16(pa2 + ko_, aN + 8192  + dA);                            \
    gload_lds16(pa3 + ko_, aN + 12288 + dA);                            \
  } while (0)
#define STAGE_B01(tt) do { const size_t ko_ = (size_t)(tt) * BK;        \
    gload_lds16(pb0 + ko_, bN + dA);                                    \
    gload_lds16(pb1 + ko_, bN + 4096 + dA);                             \
  } while (0)
#define STAGE_B23(tt) do { const size_t ko_ = (size_t)(tt) * BK;        \
    gload_lds16(pb2 + ko_, bN + 8192  + dA);                            \
    gload_lds16(pb3 + ko_, bN + 12288 + dA);                            \
  } while (0)

  // ---- fragment-read constants (R6-verified) ----
  const int l15     = lane & 15;
  const int quad    = lane >> 4;
  const int physA0  = quad ^ (l15 & 7);
  const int aRowOff = (wm * 128 + l15) * 64;   // + mi*1024
  const int bRowOff = (wn * 64  + l15) * 64;   // + ni*1024

  f32x4 acc[8][4];
  #pragma unroll
  for (int i = 0; i < 8; ++i)
    #pragma unroll
    for (int j = 0; j < 4; ++j)
      acc[i][j] = {0.f, 0.f, 0.f, 0.f};

  // ---- prologue: stage tile 0 into slot 0, cold drain ----
  {
    __bf16* aN = aBase0;
    __bf16* bN = bBase0;
    STAGE_A(0); STAGE_B01(0); STAGE_B23(0);
    asm volatile("s_waitcnt vmcnt(0)" ::: "memory");
    __builtin_amdgcn_s_barrier();
    __builtin_amdgcn_sched_barrier(0);
  }

  for (int t = 0; t < NT; ++t) {
    const int cs = t & 1;
    const __bf16* const aC = aBase0 + cs * SLOT_ELEMS;
    const __bf16* const bC = bBase0 + cs * SLOT_ELEMS;
    __bf16* const aN = aBase0 + (cs ^ 1) * SLOT_ELEMS;  // holds t-1: dead
    __bf16* const bN = bBase0 + (cs ^ 1) * SLOT_ELEMS;
    const bool st = (t + 1 < NT);

    bf16x8 bfr[4][2];   // B frags, held across the 4 phases

    #pragma unroll
    for (int q = 0; q < 4; ++q) {
      // --- phase q: ds-reads for this quadrant (+B at q==0), stage, MFMA ---
      bf16x8 aA[2][2];
      #pragma unroll
      for (int i = 0; i < 2; ++i)
        #pragma unroll
        for (int ks = 0; ks < 2; ++ks)
          aA[i][ks] = *(const bf16x8*)(
              aC + aRowOff + (2 * q + i) * 1024 + (physA0 ^ (ks << 2)) * 8);
      if (q == 0) {
        #pragma unroll
        for (int ni = 0; ni < 4; ++ni)
          #pragma unroll
          for (int ks = 0; ks < 2; ++ks)
            bfr[ni][ks] = *(const bf16x8*)(
                bC + bRowOff + ni * 1024 + (physA0 ^ (ks << 2)) * 8);
      }
      if (st) {
        if (q == 0)      STAGE_A(t + 1);
        else if (q == 1) STAGE_B01(t + 1);
        else if (q == 2) STAGE_B23(t + 1);
      }

      __builtin_amdgcn_s_barrier();
      __builtin_amdgcn_sched_barrier(0);

      __builtin_amdgcn_s_setprio(1);
      #pragma unroll
      for (int i = 0; i < 2; ++i)
        #pragma unroll
        for (int ni = 0; ni < 4; ++ni)
          #pragma unroll
          for (int ks = 0; ks < 2; ++ks)
            acc[2 * q + i][ni] = __builtin_amdgcn_mfma_f32_16x16x32_bf16(
                aA[i][ks], bfr[ni][ks], acc[2 * q + i][ni], 0, 0, 0);
      __builtin_amdgcn_s_setprio(0);

      if (q == 3 && st) {
        // own 8 loads for tile t+1 landed; barrier makes it cross-wave
        asm volatile("s_waitcnt vmcnt(0)" ::: "memory");
      }
      __builtin_amdgcn_s_barrier();
      __builtin_amdgcn_sched_barrier(0);
    }
  }
#undef STAGE_A
#undef STAGE_B01
#undef STAGE_B23

  // ---- epilogue: scale+bias, f32 stores (R6-verified mapping) ----
  const int colb = n0 + wn * 64 + l15;
  const int rowb = m0 + wm * 128 + quad * 4;
  #pragma unroll
  for (int ni = 0; ni < 4; ++ni) {
    const int col = colb + ni * 16;
    const float sc = S[col];
    const float bb = Bias[col];
    #pragma unroll
    for (int mi = 0; mi < 8; ++mi) {
      const int row = rowb + mi * 16;
      f32x4 a = acc[mi][ni];
      #pragma unroll
      for (int j = 0; j < 4; ++j)
        O[(size_t)(row + j) * N_TOT + col] = a[j] * sc + bb;
    }
  }
}

// ---------------- fallback: fused kernel (ws too small) ----------------
#define FBM 128
#define FBN 128
#define FBK 32
#define BSTRIDE 40
__device__ __forceinline__ int swz_s(int row) {
  return (row & 3) ^ ((row >> 2) & 1);
}
__global__ void __launch_bounds__(256)
w8a16_gemm_fused(const float* __restrict__ A, const int* __restrict__ Q,
                 const float* __restrict__ S, const float* __restrict__ Bias,
                 float* __restrict__ O)
{
  __shared__ __bf16 a_lds[FBM * FBK];
  __shared__ __bf16 b_lds[FBN * BSTRIDE];
  const int tid = threadIdx.x, lane = tid & 63, wv = tid >> 6;
  const int bid = blockIdx.x;
  const int swz = (bid & 7) * 1024 + (bid >> 3);
  const int bx = swz >> 6, by = swz & 63;
  const int m0 = by * FBM, n0 = bx * FBN;
  const int mA0 = tid >> 2, mA1 = (256 + tid) >> 2;
  const int kcA = tid & 3;
  const int kp0 = kcA ^ swz_s(mA0), kp1 = kcA ^ swz_s(mA1);
  const float* pA0 = A + (size_t)(m0 + mA0) * K_TOT + kcA * 8;
  const float* pA1 = A + (size_t)(m0 + mA1) * K_TOT + kcA * 8;
  __bf16* dA0 = a_lds + mA0 * FBK + kp0 * 8;
  __bf16* dA1 = a_lds + mA1 * FBK + kp1 * 8;
  const int nB = tid & 127, kg = (tid >> 7) * 16;
  const int* pQ = Q + (size_t)kg * N_TOT + n0 + nB;
  __bf16* dB = b_lds + nB * BSTRIDE + kg;
  const int wr = (wv >> 1) * 64, wc = (wv & 1) * 64;
  const int r15 = lane & 15, kgrp = lane >> 4;
  const int selA = kgrp ^ swz_s(r15);
  const __bf16* aRd = a_lds + (wr + r15) * FBK + selA * 8;
  const __bf16* bRd = b_lds + (wc + r15) * BSTRIDE + kgrp * 8;
  f32x4 acc[4][4];
  #pragma unroll
  for (int i = 0; i < 4; ++i)
    #pragma unroll
    for (int j = 0; j < 4; ++j) acc[i][j] = {0.f, 0.f, 0.f, 0.f};
  for (int kt = 0; kt < K_TOT / FBK; ++kt) {
    f32x4 a0lo = *(const f32x4*)(pA0), a0hi = *(const f32x4*)(pA0 + 4);
    f32x4 a1lo = *(const f32x4*)(pA1), a1hi = *(const f32x4*)(pA1 + 4);
    pA0 += FBK; pA1 += FBK;
    bf16x8 a0, a1;
    #pragma unroll
    for (int i = 0; i < 4; ++i) {
      a0[i] = (__bf16)a0lo[i]; a0[i + 4] = (__bf16)a0hi[i];
      a1[i] = (__bf16)a1lo[i]; a1[i + 4] = (__bf16)a1hi[i];
    }
    int qv[16];
    #pragma unroll
    for (int i = 0; i < 16; ++i) qv[i] = pQ[(size_t)i * N_TOT];
    pQ += (size_t)FBK * N_TOT;
    bf16x8 v0, v1;
    #pragma unroll
    for (int i = 0; i < 8; ++i) { v0[i] = (__bf16)(float)qv[i]; v1[i] = (__bf16)(float)qv[i + 8]; }
    *(bf16x8*)dA0 = a0; *(bf16x8*)dA1 = a1;
    *(bf16x8*)(dB) = v0; *(bf16x8*)(dB + 8) = v1;
    __syncthreads();
    bf16x8 af[4], bfr[4];
    #pragma unroll
    for (int mi = 0; mi < 4; ++mi) af[mi] = *(const bf16x8*)(aRd + mi * 16 * FBK);
    #pragma unroll
    for (int ni = 0; ni < 4; ++ni) bfr[ni] = *(const bf16x8*)(bRd + ni * 16 * BSTRIDE);
    #pragma unroll
    for (int mi = 0; mi < 4; ++mi)
      #pragma unroll
      for (int ni = 0; ni < 4; ++ni)
        acc[mi][ni] = __builtin_amdgcn_mfma_f32_16x16x32_bf16(af[mi], bfr[ni], acc[mi][ni], 0, 0, 0);
    __syncthreads();
  }
  const int colb = n0 + wc + r15, rowb = m0 + wr + kgrp * 4;
  #pragma unroll
  for (int ni = 0; ni < 4; ++ni) {
    const int col = colb + ni * 16;
    const float sc = S[col], bb = Bias[col];
    #pragma unroll
    for (int mi = 0; mi < 4; ++mi) {
      const int row = rowb + mi * 16;
      f32x4 a = acc[mi][ni];
      #pragma unroll
      for (int j = 0; j < 4; ++j)
        O[(size_t)(row + j) * N_TOT + col] = a[j] * sc + bb;
    }
  }
}

extern "C" void kernel_launch(void* const* d_in, const int* in_sizes, int n_in,
                              void* d_out, int out_size, void* d_ws, size_t ws_size,
                              hipStream_t stream) {
  const float* A    = (const float*)d_in[0];
  const int*   Q    = (const int*)d_in[1];
  const float* S    = (const float*)d_in[2];
  const float* Bias = (const float*)d_in[3];
  float*       O    = (float*)d_out;

  const size_t A_BYTES = (size_t)M_TOT * K_TOT * 2;   // 64 MiB
  const size_t B_BYTES = (size_t)N_TOT * K_TOT * 2;   // 128 MiB

  if (ws_size >= A_BYTES + B_BYTES) {
    __bf16* Abf = (__bf16*)d_ws;
    __bf16* Bt  = (__bf16*)((char*)d_ws + A_BYTES);
    cvt_a_kernel<<<dim3(16384), dim3(256), 0, stream>>>(A, Abf);
    transpose_q_kernel<<<dim3(16384), dim3(256), 0, stream>>>(Q, Bt);
    // grid = (M/256)*(N/256) = 32*64 = 2048 blocks, 512 threads, 128 KB LDS
    w8a16_gemm_ws<<<dim3(2048), dim3(512), 131072, stream>>>(Abf, Bt, S, Bias, O);
  } else {
    w8a16_gemm_fused<<<dim3(8192), dim3(256), 0, stream>>>(A, Q, S, Bias, O);
  }
}

// Round 8
// 1376.545 us; speedup vs baseline: 1.0257x; 1.0257x over previous
//
#include <hip/hip_runtime.h>
#include <stdint.h>

// W8A16 GEMM: out[m,n] = s[n] * sum_k a[m,k] * q_int8[k,n] + bias[n]
// M=8192, N=16384, K=4096. Harness dtypes: A,S,Bias f32; Q int32; OUT f32.
//
// Round 8: 256x256 / BK=32 / 8 waves / 3-slot LDS ring (96 KB), counted
// vmcnt(4) (never drain in steady state), stage 2 tiles ahead, ONE barrier
// per K-tile, monolithic compute body (compiler-scheduled interleave).

typedef __bf16 bf16x8 __attribute__((ext_vector_type(8)));
typedef float  f32x4  __attribute__((ext_vector_type(4)));

#define M_TOT 8192
#define N_TOT 16384
#define K_TOT 4096
#define BM 256
#define BN 256
#define BK 32
#define NT (K_TOT / BK)        // 128 K-tiles
#define SLOT_ELEMS 8192        // 256 rows * 32 cols bf16 = 16 KB per operand slot

__device__ __forceinline__ void gload_lds16(const void* g, void* l) {
  __builtin_amdgcn_global_load_lds(
      (const __attribute__((address_space(1))) unsigned int*)g,
      (__attribute__((address_space(3))) unsigned int*)l,
      16, 0, 0);
}

// chunk swizzle for 4 chunks/row: s(row) = (row&3) ^ ((row>>2)&1)
__device__ __forceinline__ int swz_s(int row) {
  return (row & 3) ^ ((row >> 2) & 1);
}

// ---------------- pre-pass 1: A f32 -> bf16 ----------------
__global__ void __launch_bounds__(256)
cvt_a_kernel(const float* __restrict__ A, __bf16* __restrict__ Abf) {
  const size_t i = ((size_t)blockIdx.x * 256 + threadIdx.x) * 8;
  f32x4 lo = *(const f32x4*)(A + i);
  f32x4 hi = *(const f32x4*)(A + i + 4);
  bf16x8 v;
  #pragma unroll
  for (int j = 0; j < 4; ++j) {
    v[j]     = (__bf16)lo[j];
    v[j + 4] = (__bf16)hi[j];
  }
  *(bf16x8*)(Abf + i) = v;
}

// ---------------- pre-pass 2: Q [K][N] int32 -> Bt [N][K] bf16 ------------
__global__ void __launch_bounds__(256)
transpose_q_kernel(const int* __restrict__ Q, __bf16* __restrict__ Bt) {
  const int bk = blockIdx.x & 63;        // 64 k-tiles
  const int bn = blockIdx.x >> 6;        // 256 n-tiles
  const int k0 = bk * 64, n0 = bn * 64;
  const int tx = threadIdx.x & 63;       // n within tile
  const int ty = threadIdx.x >> 6;       // k-chunk of 16
  const int kb = k0 + ty * 16;
  const int n  = n0 + tx;
  int q[16];
  #pragma unroll
  for (int i = 0; i < 16; ++i)
    q[i] = Q[(size_t)(kb + i) * N_TOT + n];
  bf16x8 v0, v1;
  #pragma unroll
  for (int i = 0; i < 8; ++i) {
    v0[i] = (__bf16)(float)q[i];
    v1[i] = (__bf16)(float)q[i + 8];
  }
  *(bf16x8*)(Bt + (size_t)n * K_TOT + kb)     = v0;
  *(bf16x8*)(Bt + (size_t)n * K_TOT + kb + 8) = v1;
}

// -------- main GEMM: 256^2 / BK=32 / 3-slot ring / counted vmcnt --------
__global__ void __launch_bounds__(512, 2)
w8a16_gemm_ws(const __bf16* __restrict__ A,   // [M,K] bf16
              const __bf16* __restrict__ Bt,  // [N,K] bf16
              const float*  __restrict__ S,
              const float*  __restrict__ Bias,
              float*        __restrict__ O)
{
  extern __shared__ __bf16 lds[];
  // A slots: lds + slot*8192 (slot=0..2); B slots: lds + 24576 + slot*8192
  __bf16* const bBase = lds + 3 * SLOT_ELEMS;

  const int tid  = threadIdx.x;
  const int lane = tid & 63;
  const int wv   = tid >> 6;     // 0..7
  const int wm   = wv >> 2;      // 0..1 : M-wave (rows wm*128)
  const int wn   = wv & 3;       // 0..3 : N-wave (cols wn*64)

  // XCD map: xcd owns 8 bx-columns; by fastest (B-panel L2-resident).
  const int bid = blockIdx.x;
  const int xcd = bid & 7;
  const int c   = bid >> 3;                 // [0,256)
  const int bx  = xcd * 8 + (c >> 5);       // [0,64)
  const int by  = c & 31;                   // [0,32)
  const int m0  = by * BM;
  const int n0  = bx * BN;

  // ---- staging geometry: chunk idx = j*512+tid (j=0,1); row = idx>>2,
  // phys chunk = idx&3; fetch logical chunk = phys ^ s(row).
  // row_j = j*128 + (tid>>2); s(row) identical for both j (128%8==0... bits ok).
  const int rr   = tid >> 2;                       // 0..127
  const int cc   = tid & 3;
  const int cswz = cc ^ swz_s(rr);
  const __bf16* paL = A  + (size_t)(m0 + rr)       * K_TOT + cswz * 8;
  const __bf16* paH = A  + (size_t)(m0 + 128 + rr) * K_TOT + cswz * 8;
  const __bf16* pbL = Bt + (size_t)(n0 + rr)       * K_TOT + cswz * 8;
  const __bf16* pbH = Bt + (size_t)(n0 + 128 + rr) * K_TOT + cswz * 8;
  const int dL = tid * 8;          // elem offset of chunk j=0
  const int dH = 4096 + tid * 8;   // elem offset of chunk j=1

#define STAGE(slot) do {                                   \
    __bf16* aS_ = lds + (slot) * SLOT_ELEMS;               \
    __bf16* bS_ = bBase + (slot) * SLOT_ELEMS;             \
    gload_lds16(paL, aS_ + dL);                            \
    gload_lds16(paH, aS_ + dH);                            \
    gload_lds16(pbL, bS_ + dL);                            \
    gload_lds16(pbH, bS_ + dH);                            \
    paL += BK; paH += BK; pbL += BK; pbH += BK;            \
  } while (0)

  // ---- fragment-read constants ----
  // frag (mi): row = wm*128 + mi*16 + l15 ; k-chunk quad = lane>>4 ;
  // phys = quad ^ s(row), s(row) == s(l15) for all mi (mi*16, wm*128 ~ 0 mod bits)
  const int l15  = lane & 15;
  const int quad = lane >> 4;
  const int sA   = swz_s(l15);
  const int aOff = (wm * 128 + l15) * BK + (quad ^ sA) * 8;  // + mi*512
  const int bOff = (wn * 64  + l15) * BK + (quad ^ sA) * 8;  // + ni*512

  f32x4 acc[8][4];
  #pragma unroll
  for (int i = 0; i < 8; ++i)
    #pragma unroll
    for (int j = 0; j < 4; ++j)
      acc[i][j] = {0.f, 0.f, 0.f, 0.f};

  // ---- prologue: stage tiles 0,1 into slots 0,1 (no wait) ----
  STAGE(0);
  STAGE(1);

  int cs = 0;   // slot of tile t
  int ns = 2;   // slot of tile t+2
  for (int t = 0; t < NT - 1; ++t) {
    // retire tile t's 4 loads (tile t+1's 4 stay in flight); publish.
    asm volatile("s_waitcnt vmcnt(4)" ::: "memory");
    __builtin_amdgcn_s_barrier();
    __builtin_amdgcn_sched_barrier(0);

    // stage tile t+2 into slot vacated by tile t-1 (dead since the barrier)
    if (t < NT - 2) STAGE(ns);

    const __bf16* aC = lds + cs * SLOT_ELEMS;
    const __bf16* bC = bBase + cs * SLOT_ELEMS;

    bf16x8 bfr[4];
    #pragma unroll
    for (int ni = 0; ni < 4; ++ni)
      bfr[ni] = *(const bf16x8*)(bC + bOff + ni * 512);
    bf16x8 af[8];
    #pragma unroll
    for (int mi = 0; mi < 8; ++mi)
      af[mi] = *(const bf16x8*)(aC + aOff + mi * 512);

    __builtin_amdgcn_s_setprio(1);
    #pragma unroll
    for (int mi = 0; mi < 8; ++mi)
      #pragma unroll
      for (int ni = 0; ni < 4; ++ni)
        acc[mi][ni] = __builtin_amdgcn_mfma_f32_16x16x32_bf16(
            af[mi], bfr[ni], acc[mi][ni], 0, 0, 0);
    __builtin_amdgcn_s_setprio(0);

    cs = (cs == 2) ? 0 : cs + 1;
    ns = (ns == 2) ? 0 : ns + 1;
  }

  // ---- tail: last tile (full drain, once) ----
  {
    asm volatile("s_waitcnt vmcnt(0)" ::: "memory");
    __builtin_amdgcn_s_barrier();
    __builtin_amdgcn_sched_barrier(0);
    const __bf16* aC = lds + cs * SLOT_ELEMS;
    const __bf16* bC = bBase + cs * SLOT_ELEMS;
    bf16x8 bfr[4];
    #pragma unroll
    for (int ni = 0; ni < 4; ++ni)
      bfr[ni] = *(const bf16x8*)(bC + bOff + ni * 512);
    bf16x8 af[8];
    #pragma unroll
    for (int mi = 0; mi < 8; ++mi)
      af[mi] = *(const bf16x8*)(aC + aOff + mi * 512);
    #pragma unroll
    for (int mi = 0; mi < 8; ++mi)
      #pragma unroll
      for (int ni = 0; ni < 4; ++ni)
        acc[mi][ni] = __builtin_amdgcn_mfma_f32_16x16x32_bf16(
            af[mi], bfr[ni], acc[mi][ni], 0, 0, 0);
  }
#undef STAGE

  // ---- epilogue: scale+bias, f32 stores ----
  // C/D per 16x16: col = lane&15, row = (lane>>4)*4 + reg  [m89-verified]
  const int colb = n0 + wn * 64 + l15;
  const int rowb = m0 + wm * 128 + quad * 4;
  #pragma unroll
  for (int ni = 0; ni < 4; ++ni) {
    const int col = colb + ni * 16;
    const float sc = S[col];
    const float bb = Bias[col];
    #pragma unroll
    for (int mi = 0; mi < 8; ++mi) {
      const int row = rowb + mi * 16;
      f32x4 a = acc[mi][ni];
      #pragma unroll
      for (int j = 0; j < 4; ++j)
        O[(size_t)(row + j) * N_TOT + col] = a[j] * sc + bb;
    }
  }
}

// ---------------- fallback: fused kernel (ws too small) ----------------
#define FBM 128
#define FBN 128
#define FBK 32
#define BSTRIDE 40
__global__ void __launch_bounds__(256)
w8a16_gemm_fused(const float* __restrict__ A, const int* __restrict__ Q,
                 const float* __restrict__ S, const float* __restrict__ Bias,
                 float* __restrict__ O)
{
  __shared__ __bf16 a_lds[FBM * FBK];
  __shared__ __bf16 b_lds[FBN * BSTRIDE];
  const int tid = threadIdx.x, lane = tid & 63, wv = tid >> 6;
  const int bid = blockIdx.x;
  const int swz = (bid & 7) * 1024 + (bid >> 3);
  const int bx = swz >> 6, by = swz & 63;
  const int m0 = by * FBM, n0 = bx * FBN;
  const int mA0 = tid >> 2, mA1 = (256 + tid) >> 2;
  const int kcA = tid & 3;
  const int kp0 = kcA ^ swz_s(mA0), kp1 = kcA ^ swz_s(mA1);
  const float* pA0 = A + (size_t)(m0 + mA0) * K_TOT + kcA * 8;
  const float* pA1 = A + (size_t)(m0 + mA1) * K_TOT + kcA * 8;
  __bf16* dA0 = a_lds + mA0 * FBK + kp0 * 8;
  __bf16* dA1 = a_lds + mA1 * FBK + kp1 * 8;
  const int nB = tid & 127, kg = (tid >> 7) * 16;
  const int* pQ = Q + (size_t)kg * N_TOT + n0 + nB;
  __bf16* dB = b_lds + nB * BSTRIDE + kg;
  const int wr = (wv >> 1) * 64, wc = (wv & 1) * 64;
  const int r15 = lane & 15, kgrp = lane >> 4;
  const int selA = kgrp ^ swz_s(r15);
  const __bf16* aRd = a_lds + (wr + r15) * FBK + selA * 8;
  const __bf16* bRd = b_lds + (wc + r15) * BSTRIDE + kgrp * 8;
  f32x4 acc[4][4];
  #pragma unroll
  for (int i = 0; i < 4; ++i)
    #pragma unroll
    for (int j = 0; j < 4; ++j) acc[i][j] = {0.f, 0.f, 0.f, 0.f};
  for (int kt = 0; kt < K_TOT / FBK; ++kt) {
    f32x4 a0lo = *(const f32x4*)(pA0), a0hi = *(const f32x4*)(pA0 + 4);
    f32x4 a1lo = *(const f32x4*)(pA1), a1hi = *(const f32x4*)(pA1 + 4);
    pA0 += FBK; pA1 += FBK;
    bf16x8 a0, a1;
    #pragma unroll
    for (int i = 0; i < 4; ++i) {
      a0[i] = (__bf16)a0lo[i]; a0[i + 4] = (__bf16)a0hi[i];
      a1[i] = (__bf16)a1lo[i]; a1[i + 4] = (__bf16)a1hi[i];
    }
    int qv[16];
    #pragma unroll
    for (int i = 0; i < 16; ++i) qv[i] = pQ[(size_t)i * N_TOT];
    pQ += (size_t)FBK * N_TOT;
    bf16x8 v0, v1;
    #pragma unroll
    for (int i = 0; i < 8; ++i) { v0[i] = (__bf16)(float)qv[i]; v1[i] = (__bf16)(float)qv[i + 8]; }
    *(bf16x8*)dA0 = a0; *(bf16x8*)dA1 = a1;
    *(bf16x8*)(dB) = v0; *(bf16x8*)(dB + 8) = v1;
    __syncthreads();
    bf16x8 af[4], bfr[4];
    #pragma unroll
    for (int mi = 0; mi < 4; ++mi) af[mi] = *(const bf16x8*)(aRd + mi * 16 * FBK);
    #pragma unroll
    for (int ni = 0; ni < 4; ++ni) bfr[ni] = *(const bf16x8*)(bRd + ni * 16 * BSTRIDE);
    #pragma unroll
    for (int mi = 0; mi < 4; ++mi)
      #pragma unroll
      for (int ni = 0; ni < 4; ++ni)
        acc[mi][ni] = __builtin_amdgcn_mfma_f32_16x16x32_bf16(af[mi], bfr[ni], acc[mi][ni], 0, 0, 0);
    __syncthreads();
  }
  const int colb = n0 + wc + r15, rowb = m0 + wr + kgrp * 4;
  #pragma unroll
  for (int ni = 0; ni < 4; ++ni) {
    const int col = colb + ni * 16;
    const float sc = S[col], bb = Bias[col];
    #pragma unroll
    for (int mi = 0; mi < 4; ++mi) {
      const int row = rowb + mi * 16;
      f32x4 a = acc[mi][ni];
      #pragma unroll
      for (int j = 0; j < 4; ++j)
        O[(size_t)(row + j) * N_TOT + col] = a[j] * sc + bb;
    }
  }
}

extern "C" void kernel_launch(void* const* d_in, const int* in_sizes, int n_in,
                              void* d_out, int out_size, void* d_ws, size_t ws_size,
                              hipStream_t stream) {
  const float* A    = (const float*)d_in[0];
  const int*   Q    = (const int*)d_in[1];
  const float* S    = (const float*)d_in[2];
  const float* Bias = (const float*)d_in[3];
  float*       O    = (float*)d_out;

  const size_t A_BYTES = (size_t)M_TOT * K_TOT * 2;   // 64 MiB
  const size_t B_BYTES = (size_t)N_TOT * K_TOT * 2;   // 128 MiB

  if (ws_size >= A_BYTES + B_BYTES) {
    __bf16* Abf = (__bf16*)d_ws;
    __bf16* Bt  = (__bf16*)((char*)d_ws + A_BYTES);
    cvt_a_kernel<<<dim3(16384), dim3(256), 0, stream>>>(A, Abf);
    transpose_q_kernel<<<dim3(16384), dim3(256), 0, stream>>>(Q, Bt);
    // grid = 32*64 = 2048 blocks, 512 threads, 96 KB dynamic LDS
    w8a16_gemm_ws<<<dim3(2048), dim3(512), 98304, stream>>>(Abf, Bt, S, Bias, O);
  } else {
    w8a16_gemm_fused<<<dim3(8192), dim3(256), 0, stream>>>(A, Q, S, Bias, O);
  }
}

// Round 9
// 1336.653 us; speedup vs baseline: 1.0563x; 1.0298x over previous
//
#include <hip/hip_runtime.h>
#include <stdint.h>

// W8A16 GEMM: out[m,n] = s[n] * sum_k a[m,k] * q_int8[k,n] + bias[n]
// M=8192, N=16384, K=4096. Harness dtypes: A,S,Bias f32; Q int32; OUT f32.
//
// Round 9: 256x256 / BK=64 / 8 waves; asymmetric ring A:3 slots (staged 2
// ahead) + B:2 slots (1 ahead) = 160 KB LDS; 4 phases/tile with barrier
// pairs; end-of-tile s_waitcnt vmcnt(4) -- A(t+2) loads stay in flight
// across the barrier (true T4 counted wait, no steady-state drain).

typedef __bf16 bf16x8 __attribute__((ext_vector_type(8)));
typedef float  f32x4  __attribute__((ext_vector_type(4)));

#define M_TOT 8192
#define N_TOT 16384
#define K_TOT 4096
#define BM 256
#define BN 256
#define BK 64
#define NT (K_TOT / BK)        // 64 K-tiles
#define SLOT_ELEMS 16384       // 256 rows * 64 cols bf16 = 32 KB per slot

__device__ __forceinline__ void gload_lds16(const void* g, void* l) {
  __builtin_amdgcn_global_load_lds(
      (const __attribute__((address_space(1))) unsigned int*)g,
      (__attribute__((address_space(3))) unsigned int*)l,
      16, 0, 0);
}

// ---------------- pre-pass 1: A f32 -> bf16 ----------------
__global__ void __launch_bounds__(256)
cvt_a_kernel(const float* __restrict__ A, __bf16* __restrict__ Abf) {
  const size_t i = ((size_t)blockIdx.x * 256 + threadIdx.x) * 8;
  f32x4 lo = *(const f32x4*)(A + i);
  f32x4 hi = *(const f32x4*)(A + i + 4);
  bf16x8 v;
  #pragma unroll
  for (int j = 0; j < 4; ++j) {
    v[j]     = (__bf16)lo[j];
    v[j + 4] = (__bf16)hi[j];
  }
  *(bf16x8*)(Abf + i) = v;
}

// ---------------- pre-pass 2: Q [K][N] int32 -> Bt [N][K] bf16 ------------
__global__ void __launch_bounds__(256)
transpose_q_kernel(const int* __restrict__ Q, __bf16* __restrict__ Bt) {
  const int bk = blockIdx.x & 63;        // 64 k-tiles
  const int bn = blockIdx.x >> 6;        // 256 n-tiles
  const int k0 = bk * 64, n0 = bn * 64;
  const int tx = threadIdx.x & 63;       // n within tile
  const int ty = threadIdx.x >> 6;       // k-chunk of 16
  const int kb = k0 + ty * 16;
  const int n  = n0 + tx;
  int q[16];
  #pragma unroll
  for (int i = 0; i < 16; ++i)
    q[i] = Q[(size_t)(kb + i) * N_TOT + n];
  bf16x8 v0, v1;
  #pragma unroll
  for (int i = 0; i < 8; ++i) {
    v0[i] = (__bf16)(float)q[i];
    v1[i] = (__bf16)(float)q[i + 8];
  }
  *(bf16x8*)(Bt + (size_t)n * K_TOT + kb)     = v0;
  *(bf16x8*)(Bt + (size_t)n * K_TOT + kb + 8) = v1;
}

// ------ main GEMM: 256^2 / BK=64 / A-3+B-2 ring / 4-phase / vmcnt(4) ------
__global__ void __launch_bounds__(512, 2)
w8a16_gemm_ws(const __bf16* __restrict__ A,   // [M,K] bf16
              const __bf16* __restrict__ Bt,  // [N,K] bf16
              const float*  __restrict__ S,
              const float*  __restrict__ Bias,
              float*        __restrict__ O)
{
  extern __shared__ __bf16 lds[];
  __bf16* const aBase = lds;                     // A: 3 slots of 32 KB
  __bf16* const bBase = lds + 3 * SLOT_ELEMS;    // B: 2 slots of 32 KB

  const int tid  = threadIdx.x;
  const int lane = tid & 63;
  const int wv   = tid >> 6;     // 0..7
  const int wm   = wv >> 2;      // 0..1 : M-wave (rows wm*128)
  const int wn   = wv & 3;       // 0..3 : N-wave (cols wn*64)

  // XCD map: xcd owns 8 bx-columns; by fastest (B-panel L2-resident).
  const int bid = blockIdx.x;
  const int xcd = bid & 7;
  const int c   = bid >> 3;                 // [0,256)
  const int bx  = xcd * 8 + (c >> 5);       // [0,64)
  const int by  = c & 31;                   // [0,32)
  const int m0  = by * BM;
  const int n0  = bx * BN;

  // ---- staging geometry (R6-verified, 0 bank conflicts) ----
  // row rr = tid>>3 (+64 per group); phys chunk = tid&7; fetch logical
  // chunk = phys ^ (rr&7)  [inverse swizzle at source, linear LDS dest].
  const int rr   = tid >> 3;                       // 0..63
  const int cswz = (tid & 7) ^ (rr & 7);
  const __bf16* pa0 = A  + (size_t)(m0 + 0   + rr) * K_TOT + cswz * 8;
  const __bf16* pa1 = A  + (size_t)(m0 + 64  + rr) * K_TOT + cswz * 8;
  const __bf16* pa2 = A  + (size_t)(m0 + 128 + rr) * K_TOT + cswz * 8;
  const __bf16* pa3 = A  + (size_t)(m0 + 192 + rr) * K_TOT + cswz * 8;
  const __bf16* pb0 = Bt + (size_t)(n0 + 0   + rr) * K_TOT + cswz * 8;
  const __bf16* pb1 = Bt + (size_t)(n0 + 64  + rr) * K_TOT + cswz * 8;
  const __bf16* pb2 = Bt + (size_t)(n0 + 128 + rr) * K_TOT + cswz * 8;
  const __bf16* pb3 = Bt + (size_t)(n0 + 192 + rr) * K_TOT + cswz * 8;
  const int dA = tid * 8;

#define STAGE_A(dst) do {                                  \
    gload_lds16(pa0, (dst) + dA);                          \
    gload_lds16(pa1, (dst) + 4096  + dA);                  \
    gload_lds16(pa2, (dst) + 8192  + dA);                  \
    gload_lds16(pa3, (dst) + 12288 + dA);                  \
    pa0 += BK; pa1 += BK; pa2 += BK; pa3 += BK;            \
  } while (0)
#define STAGE_B(dst) do {                                  \
    gload_lds16(pb0, (dst) + dA);                          \
    gload_lds16(pb1, (dst) + 4096  + dA);                  \
    gload_lds16(pb2, (dst) + 8192  + dA);                  \
    gload_lds16(pb3, (dst) + 12288 + dA);                  \
    pb0 += BK; pb1 += BK; pb2 += BK; pb3 += BK;            \
  } while (0)

  // ---- fragment-read constants (R6-verified) ----
  const int l15     = lane & 15;
  const int quad    = lane >> 4;
  const int physA0  = quad ^ (l15 & 7);
  const int aRowOff = (wm * 128 + l15) * 64;   // + mi*1024
  const int bRowOff = (wn * 64  + l15) * 64;   // + ni*1024

  f32x4 acc[8][4];
  #pragma unroll
  for (int i = 0; i < 8; ++i)
    #pragma unroll
    for (int j = 0; j < 4; ++j)
      acc[i][j] = {0.f, 0.f, 0.f, 0.f};

  // ---- prologue: A(0)->slot0, B(0)->slot0, A(1)->slot1 ----
  STAGE_A(aBase);
  STAGE_B(bBase);
  STAGE_A(aBase + SLOT_ELEMS);
  // retire A(0)+B(0) (8 oldest); A(1)'s 4 stay in flight
  asm volatile("s_waitcnt vmcnt(4)" ::: "memory");
  __builtin_amdgcn_s_barrier();
  __builtin_amdgcn_sched_barrier(0);

  int csA = 0;   // A slot of tile t
  int nsA = 2;   // A slot of tile t+2
  for (int t = 0; t < NT; ++t) {
    const __bf16* const aC = aBase + csA * SLOT_ELEMS;
    const __bf16* const bC = bBase + (t & 1) * SLOT_ELEMS;
    __bf16* const aN = aBase + nsA * SLOT_ELEMS;          // slot of t-1: dead
    __bf16* const bN = bBase + ((t + 1) & 1) * SLOT_ELEMS;

    bf16x8 bfr[4][2];
    bf16x8 aA[2][2];

    // ================= phase 0: all B frags + A quad0; stage B(t+1) ======
    #pragma unroll
    for (int ni = 0; ni < 4; ++ni)
      #pragma unroll
      for (int ks = 0; ks < 2; ++ks)
        bfr[ni][ks] = *(const bf16x8*)(
            bC + bRowOff + ni * 1024 + (physA0 ^ (ks << 2)) * 8);
    #pragma unroll
    for (int i = 0; i < 2; ++i)
      #pragma unroll
      for (int ks = 0; ks < 2; ++ks)
        aA[i][ks] = *(const bf16x8*)(
            aC + aRowOff + i * 1024 + (physA0 ^ (ks << 2)) * 8);
    if (t + 1 < NT) STAGE_B(bN);
    __builtin_amdgcn_s_barrier();
    __builtin_amdgcn_sched_barrier(0);
    __builtin_amdgcn_s_setprio(1);
    #pragma unroll
    for (int i = 0; i < 2; ++i)
      #pragma unroll
      for (int ni = 0; ni < 4; ++ni)
        #pragma unroll
        for (int ks = 0; ks < 2; ++ks)
          acc[i][ni] = __builtin_amdgcn_mfma_f32_16x16x32_bf16(
              aA[i][ks], bfr[ni][ks], acc[i][ni], 0, 0, 0);
    __builtin_amdgcn_s_setprio(0);
    __builtin_amdgcn_s_barrier();
    __builtin_amdgcn_sched_barrier(0);

    // ================= phase 1: A quad1; stage A(t+2) ====================
    #pragma unroll
    for (int i = 0; i < 2; ++i)
      #pragma unroll
      for (int ks = 0; ks < 2; ++ks)
        aA[i][ks] = *(const bf16x8*)(
            aC + aRowOff + (2 + i) * 1024 + (physA0 ^ (ks << 2)) * 8);
    if (t + 2 < NT) STAGE_A(aN);
    __builtin_amdgcn_s_barrier();
    __builtin_amdgcn_sched_barrier(0);
    __builtin_amdgcn_s_setprio(1);
    #pragma unroll
    for (int i = 0; i < 2; ++i)
      #pragma unroll
      for (int ni = 0; ni < 4; ++ni)
        #pragma unroll
        for (int ks = 0; ks < 2; ++ks)
          acc[2 + i][ni] = __builtin_amdgcn_mfma_f32_16x16x32_bf16(
              aA[i][ks], bfr[ni][ks], acc[2 + i][ni], 0, 0, 0);
    __builtin_amdgcn_s_setprio(0);
    __builtin_amdgcn_s_barrier();
    __builtin_amdgcn_sched_barrier(0);

    // ================= phase 2: A quad2 ==================================
    #pragma unroll
    for (int i = 0; i < 2; ++i)
      #pragma unroll
      for (int ks = 0; ks < 2; ++ks)
        aA[i][ks] = *(const bf16x8*)(
            aC + aRowOff + (4 + i) * 1024 + (physA0 ^ (ks << 2)) * 8);
    __builtin_amdgcn_s_barrier();
    __builtin_amdgcn_sched_barrier(0);
    __builtin_amdgcn_s_setprio(1);
    #pragma unroll
    for (int i = 0; i < 2; ++i)
      #pragma unroll
      for (int ni = 0; ni < 4; ++ni)
        #pragma unroll
        for (int ks = 0; ks < 2; ++ks)
          acc[4 + i][ni] = __builtin_amdgcn_mfma_f32_16x16x32_bf16(
              aA[i][ks], bfr[ni][ks], acc[4 + i][ni], 0, 0, 0);
    __builtin_amdgcn_s_setprio(0);
    __builtin_amdgcn_s_barrier();
    __builtin_amdgcn_sched_barrier(0);

    // ================= phase 3: A quad3; counted wait ====================
    #pragma unroll
    for (int i = 0; i < 2; ++i)
      #pragma unroll
      for (int ks = 0; ks < 2; ++ks)
        aA[i][ks] = *(const bf16x8*)(
            aC + aRowOff + (6 + i) * 1024 + (physA0 ^ (ks << 2)) * 8);
    __builtin_amdgcn_s_barrier();
    __builtin_amdgcn_sched_barrier(0);
    __builtin_amdgcn_s_setprio(1);
    #pragma unroll
    for (int i = 0; i < 2; ++i)
      #pragma unroll
      for (int ni = 0; ni < 4; ++ni)
        #pragma unroll
        for (int ks = 0; ks < 2; ++ks)
          acc[6 + i][ni] = __builtin_amdgcn_mfma_f32_16x16x32_bf16(
              aA[i][ks], bfr[ni][ks], acc[6 + i][ni], 0, 0, 0);
    __builtin_amdgcn_s_setprio(0);
    // retire A(t+1)+B(t+1); A(t+2)'s 4 loads stay in flight (tail: drain)
    if (t < NT - 2) {
      asm volatile("s_waitcnt vmcnt(4)" ::: "memory");
    } else {
      asm volatile("s_waitcnt vmcnt(0)" ::: "memory");
    }
    __builtin_amdgcn_s_barrier();
    __builtin_amdgcn_sched_barrier(0);

    csA = (csA == 2) ? 0 : csA + 1;
    nsA = (nsA == 2) ? 0 : nsA + 1;
  }
#undef STAGE_A
#undef STAGE_B

  // ---- epilogue: scale+bias, f32 stores ----
  // C/D per 16x16: col = lane&15, row = (lane>>4)*4 + reg  [m89-verified]
  const int colb = n0 + wn * 64 + l15;
  const int rowb = m0 + wm * 128 + quad * 4;
  #pragma unroll
  for (int ni = 0; ni < 4; ++ni) {
    const int col = colb + ni * 16;
    const float sc = S[col];
    const float bb = Bias[col];
    #pragma unroll
    for (int mi = 0; mi < 8; ++mi) {
      const int row = rowb + mi * 16;
      f32x4 a = acc[mi][ni];
      #pragma unroll
      for (int j = 0; j < 4; ++j)
        O[(size_t)(row + j) * N_TOT + col] = a[j] * sc + bb;
    }
  }
}

// ---------------- fallback: fused kernel (ws too small) ----------------
#define FBM 128
#define FBN 128
#define FBK 32
#define BSTRIDE 40
__device__ __forceinline__ int swz_s(int row) {
  return (row & 3) ^ ((row >> 2) & 1);
}
__global__ void __launch_bounds__(256)
w8a16_gemm_fused(const float* __restrict__ A, const int* __restrict__ Q,
                 const float* __restrict__ S, const float* __restrict__ Bias,
                 float* __restrict__ O)
{
  __shared__ __bf16 a_lds[FBM * FBK];
  __shared__ __bf16 b_lds[FBN * BSTRIDE];
  const int tid = threadIdx.x, lane = tid & 63, wv = tid >> 6;
  const int bid = blockIdx.x;
  const int swz = (bid & 7) * 1024 + (bid >> 3);
  const int bx = swz >> 6, by = swz & 63;
  const int m0 = by * FBM, n0 = bx * FBN;
  const int mA0 = tid >> 2, mA1 = (256 + tid) >> 2;
  const int kcA = tid & 3;
  const int kp0 = kcA ^ swz_s(mA0), kp1 = kcA ^ swz_s(mA1);
  const float* pA0 = A + (size_t)(m0 + mA0) * K_TOT + kcA * 8;
  const float* pA1 = A + (size_t)(m0 + mA1) * K_TOT + kcA * 8;
  __bf16* dA0 = a_lds + mA0 * FBK + kp0 * 8;
  __bf16* dA1 = a_lds + mA1 * FBK + kp1 * 8;
  const int nB = tid & 127, kg = (tid >> 7) * 16;
  const int* pQ = Q + (size_t)kg * N_TOT + n0 + nB;
  __bf16* dB = b_lds + nB * BSTRIDE + kg;
  const int wr = (wv >> 1) * 64, wc = (wv & 1) * 64;
  const int r15 = lane & 15, kgrp = lane >> 4;
  const int selA = kgrp ^ swz_s(r15);
  const __bf16* aRd = a_lds + (wr + r15) * FBK + selA * 8;
  const __bf16* bRd = b_lds + (wc + r15) * BSTRIDE + kgrp * 8;
  f32x4 acc[4][4];
  #pragma unroll
  for (int i = 0; i < 4; ++i)
    #pragma unroll
    for (int j = 0; j < 4; ++j) acc[i][j] = {0.f, 0.f, 0.f, 0.f};
  for (int kt = 0; kt < K_TOT / FBK; ++kt) {
    f32x4 a0lo = *(const f32x4*)(pA0), a0hi = *(const f32x4*)(pA0 + 4);
    f32x4 a1lo = *(const f32x4*)(pA1), a1hi = *(const f32x4*)(pA1 + 4);
    pA0 += FBK; pA1 += FBK;
    bf16x8 a0, a1;
    #pragma unroll
    for (int i = 0; i < 4; ++i) {
      a0[i] = (__bf16)a0lo[i]; a0[i + 4] = (__bf16)a0hi[i];
      a1[i] = (__bf16)a1lo[i]; a1[i + 4] = (__bf16)a1hi[i];
    }
    int qv[16];
    #pragma unroll
    for (int i = 0; i < 16; ++i) qv[i] = pQ[(size_t)i * N_TOT];
    pQ += (size_t)FBK * N_TOT;
    bf16x8 v0, v1;
    #pragma unroll
    for (int i = 0; i < 8; ++i) { v0[i] = (__bf16)(float)qv[i]; v1[i] = (__bf16)(float)qv[i + 8]; }
    *(bf16x8*)dA0 = a0; *(bf16x8*)dA1 = a1;
    *(bf16x8*)(dB) = v0; *(bf16x8*)(dB + 8) = v1;
    __syncthreads();
    bf16x8 af[4], bfr[4];
    #pragma unroll
    for (int mi = 0; mi < 4; ++mi) af[mi] = *(const bf16x8*)(aRd + mi * 16 * FBK);
    #pragma unroll
    for (int ni = 0; ni < 4; ++ni) bfr[ni] = *(const bf16x8*)(bRd + ni * 16 * BSTRIDE);
    #pragma unroll
    for (int mi = 0; mi < 4; ++mi)
      #pragma unroll
      for (int ni = 0; ni < 4; ++ni)
        acc[mi][ni] = __builtin_amdgcn_mfma_f32_16x16x32_bf16(af[mi], bfr[ni], acc[mi][ni], 0, 0, 0);
    __syncthreads();
  }
  const int colb = n0 + wc + r15, rowb = m0 + wr + kgrp * 4;
  #pragma unroll
  for (int ni = 0; ni < 4; ++ni) {
    const int col = colb + ni * 16;
    const float sc = S[col], bb = Bias[col];
    #pragma unroll
    for (int mi = 0; mi < 4; ++mi) {
      const int row = rowb + mi * 16;
      f32x4 a = acc[mi][ni];
      #pragma unroll
      for (int j = 0; j < 4; ++j)
        O[(size_t)(row + j) * N_TOT + col] = a[j] * sc + bb;
    }
  }
}

extern "C" void kernel_launch(void* const* d_in, const int* in_sizes, int n_in,
                              void* d_out, int out_size, void* d_ws, size_t ws_size,
                              hipStream_t stream) {
  const float* A    = (const float*)d_in[0];
  const int*   Q    = (const int*)d_in[1];
  const float* S    = (const float*)d_in[2];
  const float* Bias = (const float*)d_in[3];
  float*       O    = (float*)d_out;

  const size_t A_BYTES = (size_t)M_TOT * K_TOT * 2;   // 64 MiB
  const size_t B_BYTES = (size_t)N_TOT * K_TOT * 2;   // 128 MiB
  const int    LDS_BYTES = 5 * SLOT_ELEMS * 2;        // 163840 (A:3 + B:2)

  if (ws_size >= A_BYTES + B_BYTES) {
    (void)hipFuncSetAttribute((const void*)w8a16_gemm_ws,
                              hipFuncAttributeMaxDynamicSharedMemorySize,
                              LDS_BYTES);
    __bf16* Abf = (__bf16*)d_ws;
    __bf16* Bt  = (__bf16*)((char*)d_ws + A_BYTES);
    cvt_a_kernel<<<dim3(16384), dim3(256), 0, stream>>>(A, Abf);
    transpose_q_kernel<<<dim3(16384), dim3(256), 0, stream>>>(Q, Bt);
    // grid = 32*64 = 2048 blocks, 512 threads, 160 KB dynamic LDS
    w8a16_gemm_ws<<<dim3(2048), dim3(512), LDS_BYTES, stream>>>(Abf, Bt, S, Bias, O);
  } else {
    w8a16_gemm_fused<<<dim3(8192), dim3(256), 0, stream>>>(A, Q, S, Bias, O);
  }
}

// Round 10
// 1282.835 us; speedup vs baseline: 1.1006x; 1.0420x over previous
//
#include <hip/hip_runtime.h>
#include <stdint.h>

// W8A16 GEMM: out[m,n] = s[n] * sum_k a[m,k] * q_int8[k,n] + bias[n]
// M=8192, N=16384, K=4096. Harness dtypes: A,S,Bias f32; Q int32; OUT f32.
//
// Round 10: split-grid A/B ablation. Same R9 structure (256^2 / BK=64 /
// A:3+B:2 ring / 4 phases / counted vmcnt(4)), templated on LOOSE:
//   V0 (by 0..15):  LOOSE=1 -> no sched_barrier(0), plain inner barriers,
//                   single "memory"-clobbered vmcnt per tile boundary.
//   V1 (by 16..31): LOOSE=0 -> R9-exact (sched_barrier after every barrier).
// Hypothesis (m141): fence pollution defeats compiler interleave and is the
// invariant 37% MfmaUtil ceiling.

typedef __bf16 bf16x8 __attribute__((ext_vector_type(8)));
typedef float  f32x4  __attribute__((ext_vector_type(4)));

#define M_TOT 8192
#define N_TOT 16384
#define K_TOT 4096
#define BM 256
#define BN 256
#define BK 64
#define NT (K_TOT / BK)        // 64 K-tiles
#define SLOT_ELEMS 16384       // 256 rows * 64 cols bf16 = 32 KB per slot

__device__ __forceinline__ void gload_lds16(const void* g, void* l) {
  __builtin_amdgcn_global_load_lds(
      (const __attribute__((address_space(1))) unsigned int*)g,
      (__attribute__((address_space(3))) unsigned int*)l,
      16, 0, 0);
}

// ---------------- pre-pass 1: A f32 -> bf16 ----------------
__global__ void __launch_bounds__(256)
cvt_a_kernel(const float* __restrict__ A, __bf16* __restrict__ Abf) {
  const size_t i = ((size_t)blockIdx.x * 256 + threadIdx.x) * 8;
  f32x4 lo = *(const f32x4*)(A + i);
  f32x4 hi = *(const f32x4*)(A + i + 4);
  bf16x8 v;
  #pragma unroll
  for (int j = 0; j < 4; ++j) {
    v[j]     = (__bf16)lo[j];
    v[j + 4] = (__bf16)hi[j];
  }
  *(bf16x8*)(Abf + i) = v;
}

// ---------------- pre-pass 2: Q [K][N] int32 -> Bt [N][K] bf16 ------------
__global__ void __launch_bounds__(256)
transpose_q_kernel(const int* __restrict__ Q, __bf16* __restrict__ Bt) {
  const int bk = blockIdx.x & 63;        // 64 k-tiles
  const int bn = blockIdx.x >> 6;        // 256 n-tiles
  const int k0 = bk * 64, n0 = bn * 64;
  const int tx = threadIdx.x & 63;       // n within tile
  const int ty = threadIdx.x >> 6;       // k-chunk of 16
  const int kb = k0 + ty * 16;
  const int n  = n0 + tx;
  int q[16];
  #pragma unroll
  for (int i = 0; i < 16; ++i)
    q[i] = Q[(size_t)(kb + i) * N_TOT + n];
  bf16x8 v0, v1;
  #pragma unroll
  for (int i = 0; i < 8; ++i) {
    v0[i] = (__bf16)(float)q[i];
    v1[i] = (__bf16)(float)q[i + 8];
  }
  *(bf16x8*)(Bt + (size_t)n * K_TOT + kb)     = v0;
  *(bf16x8*)(Bt + (size_t)n * K_TOT + kb + 8) = v1;
}

// ------ main GEMM: 256^2 / BK=64 / A-3+B-2 ring / 4-phase / vmcnt(4) ------
template<int LOOSE>
__global__ void __launch_bounds__(512, 2)
w8a16_gemm_ws(const __bf16* __restrict__ A,   // [M,K] bf16
              const __bf16* __restrict__ Bt,  // [N,K] bf16
              const float*  __restrict__ S,
              const float*  __restrict__ Bias,
              float*        __restrict__ O,
              int m_base)                     // by = m_base + (c & 15)
{
  extern __shared__ __bf16 lds[];
  __bf16* const aBase = lds;                     // A: 3 slots of 32 KB
  __bf16* const bBase = lds + 3 * SLOT_ELEMS;    // B: 2 slots of 32 KB

  const int tid  = threadIdx.x;
  const int lane = tid & 63;
  const int wv   = tid >> 6;     // 0..7
  const int wm   = wv >> 2;      // 0..1 : M-wave (rows wm*128)
  const int wn   = wv & 3;       // 0..3 : N-wave (cols wn*64)

  // XCD map over the 1024-block half-grid: xcd owns 8 bx-columns; by fastest.
  const int bid = blockIdx.x;
  const int xcd = bid & 7;
  const int c   = bid >> 3;                 // [0,128)
  const int bx  = xcd * 8 + (c >> 4);       // [0,64)
  const int by  = m_base + (c & 15);        // half of [0,32)
  const int m0  = by * BM;
  const int n0  = bx * BN;

  // ---- staging geometry (R6-verified, 0 bank conflicts) ----
  const int rr   = tid >> 3;                       // 0..63
  const int cswz = (tid & 7) ^ (rr & 7);
  const __bf16* pa0 = A  + (size_t)(m0 + 0   + rr) * K_TOT + cswz * 8;
  const __bf16* pa1 = A  + (size_t)(m0 + 64  + rr) * K_TOT + cswz * 8;
  const __bf16* pa2 = A  + (size_t)(m0 + 128 + rr) * K_TOT + cswz * 8;
  const __bf16* pa3 = A  + (size_t)(m0 + 192 + rr) * K_TOT + cswz * 8;
  const __bf16* pb0 = Bt + (size_t)(n0 + 0   + rr) * K_TOT + cswz * 8;
  const __bf16* pb1 = Bt + (size_t)(n0 + 64  + rr) * K_TOT + cswz * 8;
  const __bf16* pb2 = Bt + (size_t)(n0 + 128 + rr) * K_TOT + cswz * 8;
  const __bf16* pb3 = Bt + (size_t)(n0 + 192 + rr) * K_TOT + cswz * 8;
  const int dA = tid * 8;

#define STAGE_A(dst) do {                                  \
    gload_lds16(pa0, (dst) + dA);                          \
    gload_lds16(pa1, (dst) + 4096  + dA);                  \
    gload_lds16(pa2, (dst) + 8192  + dA);                  \
    gload_lds16(pa3, (dst) + 12288 + dA);                  \
    pa0 += BK; pa1 += BK; pa2 += BK; pa3 += BK;            \
  } while (0)
#define STAGE_B(dst) do {                                  \
    gload_lds16(pb0, (dst) + dA);                          \
    gload_lds16(pb1, (dst) + 4096  + dA);                  \
    gload_lds16(pb2, (dst) + 8192  + dA);                  \
    gload_lds16(pb3, (dst) + 12288 + dA);                  \
    pb0 += BK; pb1 += BK; pb2 += BK; pb3 += BK;            \
  } while (0)
// inner barrier: pinned adds sched_barrier(0); loose is a plain s_barrier
#define IBAR() do {                                        \
    __builtin_amdgcn_s_barrier();                          \
    if constexpr (!LOOSE) __builtin_amdgcn_sched_barrier(0); \
  } while (0)

  // ---- fragment-read constants (R6-verified) ----
  const int l15     = lane & 15;
  const int quad    = lane >> 4;
  const int physA0  = quad ^ (l15 & 7);
  const int aRowOff = (wm * 128 + l15) * 64;   // + mi*1024
  const int bRowOff = (wn * 64  + l15) * 64;   // + ni*1024

  f32x4 acc[8][4];
  #pragma unroll
  for (int i = 0; i < 8; ++i)
    #pragma unroll
    for (int j = 0; j < 4; ++j)
      acc[i][j] = {0.f, 0.f, 0.f, 0.f};

  // ---- prologue: A(0)->slot0, B(0)->slot0, A(1)->slot1 ----
  STAGE_A(aBase);
  STAGE_B(bBase);
  STAGE_A(aBase + SLOT_ELEMS);
  asm volatile("s_waitcnt vmcnt(4)" ::: "memory");
  __builtin_amdgcn_s_barrier();
  __builtin_amdgcn_sched_barrier(0);

  int csA = 0;   // A slot of tile t
  int nsA = 2;   // A slot of tile t+2
  for (int t = 0; t < NT; ++t) {
    const __bf16* const aC = aBase + csA * SLOT_ELEMS;
    const __bf16* const bC = bBase + (t & 1) * SLOT_ELEMS;
    __bf16* const aN = aBase + nsA * SLOT_ELEMS;          // slot of t-1: dead
    __bf16* const bN = bBase + ((t + 1) & 1) * SLOT_ELEMS;

    bf16x8 bfr[4][2];
    bf16x8 aA[2][2];

    // ================= phase 0: all B frags + A quad0; stage B(t+1) ======
    #pragma unroll
    for (int ni = 0; ni < 4; ++ni)
      #pragma unroll
      for (int ks = 0; ks < 2; ++ks)
        bfr[ni][ks] = *(const bf16x8*)(
            bC + bRowOff + ni * 1024 + (physA0 ^ (ks << 2)) * 8);
    #pragma unroll
    for (int i = 0; i < 2; ++i)
      #pragma unroll
      for (int ks = 0; ks < 2; ++ks)
        aA[i][ks] = *(const bf16x8*)(
            aC + aRowOff + i * 1024 + (physA0 ^ (ks << 2)) * 8);
    if (t + 1 < NT) STAGE_B(bN);
    IBAR();
    __builtin_amdgcn_s_setprio(1);
    #pragma unroll
    for (int i = 0; i < 2; ++i)
      #pragma unroll
      for (int ni = 0; ni < 4; ++ni)
        #pragma unroll
        for (int ks = 0; ks < 2; ++ks)
          acc[i][ni] = __builtin_amdgcn_mfma_f32_16x16x32_bf16(
              aA[i][ks], bfr[ni][ks], acc[i][ni], 0, 0, 0);
    __builtin_amdgcn_s_setprio(0);
    IBAR();

    // ================= phase 1: A quad1; stage A(t+2) ====================
    #pragma unroll
    for (int i = 0; i < 2; ++i)
      #pragma unroll
      for (int ks = 0; ks < 2; ++ks)
        aA[i][ks] = *(const bf16x8*)(
            aC + aRowOff + (2 + i) * 1024 + (physA0 ^ (ks << 2)) * 8);
    if (t + 2 < NT) STAGE_A(aN);
    IBAR();
    __builtin_amdgcn_s_setprio(1);
    #pragma unroll
    for (int i = 0; i < 2; ++i)
      #pragma unroll
      for (int ni = 0; ni < 4; ++ni)
        #pragma unroll
        for (int ks = 0; ks < 2; ++ks)
          acc[2 + i][ni] = __builtin_amdgcn_mfma_f32_16x16x32_bf16(
              aA[i][ks], bfr[ni][ks], acc[2 + i][ni], 0, 0, 0);
    __builtin_amdgcn_s_setprio(0);
    IBAR();

    // ================= phase 2: A quad2 ==================================
    #pragma unroll
    for (int i = 0; i < 2; ++i)
      #pragma unroll
      for (int ks = 0; ks < 2; ++ks)
        aA[i][ks] = *(const bf16x8*)(
            aC + aRowOff + (4 + i) * 1024 + (physA0 ^ (ks << 2)) * 8);
    IBAR();
    __builtin_amdgcn_s_setprio(1);
    #pragma unroll
    for (int i = 0; i < 2; ++i)
      #pragma unroll
      for (int ni = 0; ni < 4; ++ni)
        #pragma unroll
        for (int ks = 0; ks < 2; ++ks)
          acc[4 + i][ni] = __builtin_amdgcn_mfma_f32_16x16x32_bf16(
              aA[i][ks], bfr[ni][ks], acc[4 + i][ni], 0, 0, 0);
    __builtin_amdgcn_s_setprio(0);
    IBAR();

    // ================= phase 3: A quad3; counted tile-boundary wait ======
    #pragma unroll
    for (int i = 0; i < 2; ++i)
      #pragma unroll
      for (int ks = 0; ks < 2; ++ks)
        aA[i][ks] = *(const bf16x8*)(
            aC + aRowOff + (6 + i) * 1024 + (physA0 ^ (ks << 2)) * 8);
    IBAR();
    __builtin_amdgcn_s_setprio(1);
    #pragma unroll
    for (int i = 0; i < 2; ++i)
      #pragma unroll
      for (int ni = 0; ni < 4; ++ni)
        #pragma unroll
        for (int ks = 0; ks < 2; ++ks)
          acc[6 + i][ni] = __builtin_amdgcn_mfma_f32_16x16x32_bf16(
              aA[i][ks], bfr[ni][ks], acc[6 + i][ni], 0, 0, 0);
    __builtin_amdgcn_s_setprio(0);
    // tile boundary: counted wait, "memory" clobber = the one compiler fence
    if (t < NT - 2) {
      asm volatile("s_waitcnt vmcnt(4)" ::: "memory");
    } else {
      asm volatile("s_waitcnt vmcnt(0)" ::: "memory");
    }
    __builtin_amdgcn_s_barrier();
    if constexpr (!LOOSE) __builtin_amdgcn_sched_barrier(0);

    csA = (csA == 2) ? 0 : csA + 1;
    nsA = (nsA == 2) ? 0 : nsA + 1;
  }
#undef STAGE_A
#undef STAGE_B
#undef IBAR

  // ---- epilogue: scale+bias, f32 stores ----
  // C/D per 16x16: col = lane&15, row = (lane>>4)*4 + reg  [m89-verified]
  const int colb = n0 + wn * 64 + l15;
  const int rowb = m0 + wm * 128 + quad * 4;
  #pragma unroll
  for (int ni = 0; ni < 4; ++ni) {
    const int col = colb + ni * 16;
    const float sc = S[col];
    const float bb = Bias[col];
    #pragma unroll
    for (int mi = 0; mi < 8; ++mi) {
      const int row = rowb + mi * 16;
      f32x4 a = acc[mi][ni];
      #pragma unroll
      for (int j = 0; j < 4; ++j)
        O[(size_t)(row + j) * N_TOT + col] = a[j] * sc + bb;
    }
  }
}

// ---------------- fallback: fused kernel (ws too small) ----------------
#define FBM 128
#define FBN 128
#define FBK 32
#define BSTRIDE 40
__device__ __forceinline__ int swz_s(int row) {
  return (row & 3) ^ ((row >> 2) & 1);
}
__global__ void __launch_bounds__(256)
w8a16_gemm_fused(const float* __restrict__ A, const int* __restrict__ Q,
                 const float* __restrict__ S, const float* __restrict__ Bias,
                 float* __restrict__ O)
{
  __shared__ __bf16 a_lds[FBM * FBK];
  __shared__ __bf16 b_lds[FBN * BSTRIDE];
  const int tid = threadIdx.x, lane = tid & 63, wv = tid >> 6;
  const int bid = blockIdx.x;
  const int swz = (bid & 7) * 1024 + (bid >> 3);
  const int bx = swz >> 6, by = swz & 63;
  const int m0 = by * FBM, n0 = bx * FBN;
  const int mA0 = tid >> 2, mA1 = (256 + tid) >> 2;
  const int kcA = tid & 3;
  const int kp0 = kcA ^ swz_s(mA0), kp1 = kcA ^ swz_s(mA1);
  const float* pA0 = A + (size_t)(m0 + mA0) * K_TOT + kcA * 8;
  const float* pA1 = A + (size_t)(m0 + mA1) * K_TOT + kcA * 8;
  __bf16* dA0 = a_lds + mA0 * FBK + kp0 * 8;
  __bf16* dA1 = a_lds + mA1 * FBK + kp1 * 8;
  const int nB = tid & 127, kg = (tid >> 7) * 16;
  const int* pQ = Q + (size_t)kg * N_TOT + n0 + nB;
  __bf16* dB = b_lds + nB * BSTRIDE + kg;
  const int wr = (wv >> 1) * 64, wc = (wv & 1) * 64;
  const int r15 = lane & 15, kgrp = lane >> 4;
  const int selA = kgrp ^ swz_s(r15);
  const __bf16* aRd = a_lds + (wr + r15) * FBK + selA * 8;
  const __bf16* bRd = b_lds + (wc + r15) * BSTRIDE + kgrp * 8;
  f32x4 acc[4][4];
  #pragma unroll
  for (int i = 0; i < 4; ++i)
    #pragma unroll
    for (int j = 0; j < 4; ++j) acc[i][j] = {0.f, 0.f, 0.f, 0.f};
  for (int kt = 0; kt < K_TOT / FBK; ++kt) {
    f32x4 a0lo = *(const f32x4*)(pA0), a0hi = *(const f32x4*)(pA0 + 4);
    f32x4 a1lo = *(const f32x4*)(pA1), a1hi = *(const f32x4*)(pA1 + 4);
    pA0 += FBK; pA1 += FBK;
    bf16x8 a0, a1;
    #pragma unroll
    for (int i = 0; i < 4; ++i) {
      a0[i] = (__bf16)a0lo[i]; a0[i + 4] = (__bf16)a0hi[i];
      a1[i] = (__bf16)a1lo[i]; a1[i + 4] = (__bf16)a1hi[i];
    }
    int qv[16];
    #pragma unroll
    for (int i = 0; i < 16; ++i) qv[i] = pQ[(size_t)i * N_TOT];
    pQ += (size_t)FBK * N_TOT;
    bf16x8 v0, v1;
    #pragma unroll
    for (int i = 0; i < 8; ++i) { v0[i] = (__bf16)(float)qv[i]; v1[i] = (__bf16)(float)qv[i + 8]; }
    *(bf16x8*)dA0 = a0; *(bf16x8*)dA1 = a1;
    *(bf16x8*)(dB) = v0; *(bf16x8*)(dB + 8) = v1;
    __syncthreads();
    bf16x8 af[4], bfr[4];
    #pragma unroll
    for (int mi = 0; mi < 4; ++mi) af[mi] = *(const bf16x8*)(aRd + mi * 16 * FBK);
    #pragma unroll
    for (int ni = 0; ni < 4; ++ni) bfr[ni] = *(const bf16x8*)(bRd + ni * 16 * BSTRIDE);
    #pragma unroll
    for (int mi = 0; mi < 4; ++mi)
      #pragma unroll
      for (int ni = 0; ni < 4; ++ni)
        acc[mi][ni] = __builtin_amdgcn_mfma_f32_16x16x32_bf16(af[mi], bfr[ni], acc[mi][ni], 0, 0, 0);
    __syncthreads();
  }
  const int colb = n0 + wc + r15, rowb = m0 + wr + kgrp * 4;
  #pragma unroll
  for (int ni = 0; ni < 4; ++ni) {
    const int col = colb + ni * 16;
    const float sc = S[col], bb = Bias[col];
    #pragma unroll
    for (int mi = 0; mi < 4; ++mi) {
      const int row = rowb + mi * 16;
      f32x4 a = acc[mi][ni];
      #pragma unroll
      for (int j = 0; j < 4; ++j)
        O[(size_t)(row + j) * N_TOT + col] = a[j] * sc + bb;
    }
  }
}

extern "C" void kernel_launch(void* const* d_in, const int* in_sizes, int n_in,
                              void* d_out, int out_size, void* d_ws, size_t ws_size,
                              hipStream_t stream) {
  const float* A    = (const float*)d_in[0];
  const int*   Q    = (const int*)d_in[1];
  const float* S    = (const float*)d_in[2];
  const float* Bias = (const float*)d_in[3];
  float*       O    = (float*)d_out;

  const size_t A_BYTES = (size_t)M_TOT * K_TOT * 2;   // 64 MiB
  const size_t B_BYTES = (size_t)N_TOT * K_TOT * 2;   // 128 MiB
  const int    LDS_BYTES = 5 * SLOT_ELEMS * 2;        // 163840 (A:3 + B:2)

  if (ws_size >= A_BYTES + B_BYTES) {
    (void)hipFuncSetAttribute((const void*)&w8a16_gemm_ws<1>,
                              hipFuncAttributeMaxDynamicSharedMemorySize,
                              LDS_BYTES);
    (void)hipFuncSetAttribute((const void*)&w8a16_gemm_ws<0>,
                              hipFuncAttributeMaxDynamicSharedMemorySize,
                              LDS_BYTES);
    __bf16* Abf = (__bf16*)d_ws;
    __bf16* Bt  = (__bf16*)((char*)d_ws + A_BYTES);
    cvt_a_kernel<<<dim3(16384), dim3(256), 0, stream>>>(A, Abf);
    transpose_q_kernel<<<dim3(16384), dim3(256), 0, stream>>>(Q, Bt);
    // A/B split: V0 (LOOSE) on by 0..15, V1 (pinned, R9-exact) on by 16..31.
    // Each: 1024 blocks, 512 threads, 160 KB dynamic LDS.
    w8a16_gemm_ws<1><<<dim3(1024), dim3(512), LDS_BYTES, stream>>>(
        Abf, Bt, S, Bias, O, 0);
    w8a16_gemm_ws<0><<<dim3(1024), dim3(512), LDS_BYTES, stream>>>(
        Abf, Bt, S, Bias, O, 16);
  } else {
    w8a16_gemm_fused<<<dim3(8192), dim3(256), 0, stream>>>(A, Q, S, Bias, O);
  }
}

// Round 11
// 1225.524 us; speedup vs baseline: 1.1521x; 1.0468x over previous
//
#include <hip/hip_runtime.h>
#include <stdint.h>

// W8A16 GEMM: out[m,n] = s[n] * sum_k a[m,k] * q_int8[k,n] + bias[n]
// M=8192, N=16384, K=4096. Harness dtypes: A,S,Bias f32; Q int32; OUT f32.
//
// Round 11: wave-staggered quadrant rotation A/B.
// Diagnosis (R10): per-CU wall 5760 cyc/tile = LDS-port (3000) + MFMA (2480)
// running SERIAL because all 8 waves are lockstep (all read, then all MFMA).
// Fix: one barrier/tile; each wave walks the 4 A-quadrants starting at
// (wv&3) -> reads of some waves overlap MFMAs of others. acc statically
// indexed; quadrant only changes wave-uniform address offsets (rule #20 safe).
//   V1 (by 0..15):  STAG=1 rotation wv&3
//   V0 (by 16..31): STAG=0 rotation 0 (control, same structure)

typedef __bf16 bf16x8 __attribute__((ext_vector_type(8)));
typedef float  f32x4  __attribute__((ext_vector_type(4)));

#define M_TOT 8192
#define N_TOT 16384
#define K_TOT 4096
#define BM 256
#define BN 256
#define BK 64
#define NT (K_TOT / BK)        // 64 K-tiles
#define SLOT_ELEMS 16384       // 256 rows * 64 cols bf16 = 32 KB per slot

__device__ __forceinline__ void gload_lds16(const void* g, void* l) {
  __builtin_amdgcn_global_load_lds(
      (const __attribute__((address_space(1))) unsigned int*)g,
      (__attribute__((address_space(3))) unsigned int*)l,
      16, 0, 0);
}

// ---------------- pre-pass 1: A f32 -> bf16 ----------------
__global__ void __launch_bounds__(256)
cvt_a_kernel(const float* __restrict__ A, __bf16* __restrict__ Abf) {
  const size_t i = ((size_t)blockIdx.x * 256 + threadIdx.x) * 8;
  f32x4 lo = *(const f32x4*)(A + i);
  f32x4 hi = *(const f32x4*)(A + i + 4);
  bf16x8 v;
  #pragma unroll
  for (int j = 0; j < 4; ++j) {
    v[j]     = (__bf16)lo[j];
    v[j + 4] = (__bf16)hi[j];
  }
  *(bf16x8*)(Abf + i) = v;
}

// ---------------- pre-pass 2: Q [K][N] int32 -> Bt [N][K] bf16 ------------
__global__ void __launch_bounds__(256)
transpose_q_kernel(const int* __restrict__ Q, __bf16* __restrict__ Bt) {
  const int bk = blockIdx.x & 63;        // 64 k-tiles
  const int bn = blockIdx.x >> 6;        // 256 n-tiles
  const int k0 = bk * 64, n0 = bn * 64;
  const int tx = threadIdx.x & 63;       // n within tile
  const int ty = threadIdx.x >> 6;       // k-chunk of 16
  const int kb = k0 + ty * 16;
  const int n  = n0 + tx;
  int q[16];
  #pragma unroll
  for (int i = 0; i < 16; ++i)
    q[i] = Q[(size_t)(kb + i) * N_TOT + n];
  bf16x8 v0, v1;
  #pragma unroll
  for (int i = 0; i < 8; ++i) {
    v0[i] = (__bf16)(float)q[i];
    v1[i] = (__bf16)(float)q[i + 8];
  }
  *(bf16x8*)(Bt + (size_t)n * K_TOT + kb)     = v0;
  *(bf16x8*)(Bt + (size_t)n * K_TOT + kb + 8) = v1;
}

// -- main GEMM: 256^2 / BK=64 / A3+B2 ring / 1 barrier/tile / stagger ------
template<int STAG>
__global__ void __launch_bounds__(512, 2)
w8a16_gemm_ws(const __bf16* __restrict__ A,   // [M,K] bf16
              const __bf16* __restrict__ Bt,  // [N,K] bf16
              const float*  __restrict__ S,
              const float*  __restrict__ Bias,
              float*        __restrict__ O,
              int m_base)                     // by = m_base + (c & 15)
{
  extern __shared__ __bf16 lds[];
  __bf16* const aBase = lds;                     // A: 3 slots of 32 KB
  __bf16* const bBase = lds + 3 * SLOT_ELEMS;    // B: 2 slots of 32 KB

  const int tid  = threadIdx.x;
  const int lane = tid & 63;
  const int wv   = tid >> 6;     // 0..7
  const int wm   = wv >> 2;      // 0..1 : M-wave (rows wm*128)
  const int wn   = wv & 3;       // 0..3 : N-wave (cols wn*64)
  const int rot  = STAG ? (wv & 3) : 0;   // quadrant rotation (wave-uniform)

  // XCD map over the 1024-block half-grid: xcd owns 8 bx-columns; by fastest.
  const int bid = blockIdx.x;
  const int xcd = bid & 7;
  const int c   = bid >> 3;                 // [0,128)
  const int bx  = xcd * 8 + (c >> 4);       // [0,64)
  const int by  = m_base + (c & 15);        // half of [0,32)
  const int m0  = by * BM;
  const int n0  = bx * BN;

  // ---- staging geometry (R6-verified, 0 bank conflicts) ----
  const int rr   = tid >> 3;                       // 0..63
  const int cswz = (tid & 7) ^ (rr & 7);
  const __bf16* pa0 = A  + (size_t)(m0 + 0   + rr) * K_TOT + cswz * 8;
  const __bf16* pa1 = A  + (size_t)(m0 + 64  + rr) * K_TOT + cswz * 8;
  const __bf16* pa2 = A  + (size_t)(m0 + 128 + rr) * K_TOT + cswz * 8;
  const __bf16* pa3 = A  + (size_t)(m0 + 192 + rr) * K_TOT + cswz * 8;
  const __bf16* pb0 = Bt + (size_t)(n0 + 0   + rr) * K_TOT + cswz * 8;
  const __bf16* pb1 = Bt + (size_t)(n0 + 64  + rr) * K_TOT + cswz * 8;
  const __bf16* pb2 = Bt + (size_t)(n0 + 128 + rr) * K_TOT + cswz * 8;
  const __bf16* pb3 = Bt + (size_t)(n0 + 192 + rr) * K_TOT + cswz * 8;
  const int dA = tid * 8;

#define STAGE_A(dst) do {                                  \
    gload_lds16(pa0, (dst) + dA);                          \
    gload_lds16(pa1, (dst) + 4096  + dA);                  \
    gload_lds16(pa2, (dst) + 8192  + dA);                  \
    gload_lds16(pa3, (dst) + 12288 + dA);                  \
    pa0 += BK; pa1 += BK; pa2 += BK; pa3 += BK;            \
  } while (0)
#define STAGE_B(dst) do {                                  \
    gload_lds16(pb0, (dst) + dA);                          \
    gload_lds16(pb1, (dst) + 4096  + dA);                  \
    gload_lds16(pb2, (dst) + 8192  + dA);                  \
    gload_lds16(pb3, (dst) + 12288 + dA);                  \
    pb0 += BK; pb1 += BK; pb2 += BK; pb3 += BK;            \
  } while (0)

  // ---- fragment-read constants ----
  // A frag row = wm*128 + qq*32 + i*16 + l15; offsets mod 8 unchanged by
  // qq*32 / i*16, so phys chunk = physA0 ^ (ks<<2) for all quadrants.
  const int l15    = lane & 15;
  const int quad   = lane >> 4;
  const int physA0 = quad ^ (l15 & 7);
  const int bRowOff = (wn * 64 + l15) * 64;    // + ni*1024

  f32x4 acc[8][4];   // acc[2*pp+i][ni] <-> quadrant (pp+rot)&3, row pair i
  #pragma unroll
  for (int i = 0; i < 8; ++i)
    #pragma unroll
    for (int j = 0; j < 4; ++j)
      acc[i][j] = {0.f, 0.f, 0.f, 0.f};

  // ---- prologue: A(0)->s0, B(0)->s0, A(1)->s1 (per-wave FIFO order) ----
  STAGE_A(aBase);
  STAGE_B(bBase);
  STAGE_A(aBase + SLOT_ELEMS);

  int csA = 0;   // A slot of tile t
  int nsA = 2;   // A slot of tile t+2
  for (int t = 0; t < NT; ++t) {
    // top of tile: retire own A(t)+B(t) (oldest); A(t+1) stays in flight.
    if (t < NT - 1) {
      asm volatile("s_waitcnt vmcnt(4)" ::: "memory");
    } else {
      asm volatile("s_waitcnt vmcnt(0)" ::: "memory");
    }
    __builtin_amdgcn_s_barrier();

    const __bf16* const aC = aBase + csA * SLOT_ELEMS;
    const __bf16* const bC = bBase + (t & 1) * SLOT_ELEMS;
    __bf16* const aN = aBase + nsA * SLOT_ELEMS;          // slot of t-1: dead
    __bf16* const bN = bBase + ((t + 1) & 1) * SLOT_ELEMS;

    bf16x8 bfr[4][2];

    #pragma unroll
    for (int pp = 0; pp < 4; ++pp) {
      const int qq = (pp + rot) & 3;                      // wave-uniform
      const __bf16* aQ = aC + (wm * 128 + qq * 32 + l15) * 64;

      bf16x8 aA[2][2];
      #pragma unroll
      for (int i = 0; i < 2; ++i)
        #pragma unroll
        for (int ks = 0; ks < 2; ++ks)
          aA[i][ks] = *(const bf16x8*)(
              aQ + i * 1024 + (physA0 ^ (ks << 2)) * 8);
      if (pp == 0) {
        #pragma unroll
        for (int ni = 0; ni < 4; ++ni)
          #pragma unroll
          for (int ks = 0; ks < 2; ++ks)
            bfr[ni][ks] = *(const bf16x8*)(
                bC + bRowOff + ni * 1024 + (physA0 ^ (ks << 2)) * 8);
      }
      if (pp == 1 && t + 1 < NT) STAGE_B(bN);
      if (pp == 2 && t + 2 < NT) STAGE_A(aN);

      __builtin_amdgcn_s_setprio(1);
      #pragma unroll
      for (int i = 0; i < 2; ++i)
        #pragma unroll
        for (int ni = 0; ni < 4; ++ni)
          #pragma unroll
          for (int ks = 0; ks < 2; ++ks)
            acc[2 * pp + i][ni] = __builtin_amdgcn_mfma_f32_16x16x32_bf16(
                aA[i][ks], bfr[ni][ks], acc[2 * pp + i][ni], 0, 0, 0);
      __builtin_amdgcn_s_setprio(0);
    }

    csA = (csA == 2) ? 0 : csA + 1;
    nsA = (nsA == 2) ? 0 : nsA + 1;
  }
#undef STAGE_A
#undef STAGE_B

  // ---- epilogue: scale+bias, f32 stores ----
  // acc[2*pp+i] holds rows qq*32 + i*16 (+ quad*4 + reg), qq=(pp+rot)&3.
  const int colb = n0 + wn * 64 + l15;
  #pragma unroll
  for (int pp = 0; pp < 4; ++pp) {
    const int qq = (pp + rot) & 3;
    const int rowq = m0 + wm * 128 + qq * 32 + quad * 4;
    #pragma unroll
    for (int i = 0; i < 2; ++i) {
      const int rowb = rowq + i * 16;
      #pragma unroll
      for (int ni = 0; ni < 4; ++ni) {
        const int col = colb + ni * 16;
        const float sc = S[col];
        const float bb = Bias[col];
        f32x4 a = acc[2 * pp + i][ni];
        #pragma unroll
        for (int j = 0; j < 4; ++j)
          O[(size_t)(rowb + j) * N_TOT + col] = a[j] * sc + bb;
      }
    }
  }
}

// ---------------- fallback: fused kernel (ws too small) ----------------
#define FBM 128
#define FBN 128
#define FBK 32
#define BSTRIDE 40
__device__ __forceinline__ int swz_s(int row) {
  return (row & 3) ^ ((row >> 2) & 1);
}
__global__ void __launch_bounds__(256)
w8a16_gemm_fused(const float* __restrict__ A, const int* __restrict__ Q,
                 const float* __restrict__ S, const float* __restrict__ Bias,
                 float* __restrict__ O)
{
  __shared__ __bf16 a_lds[FBM * FBK];
  __shared__ __bf16 b_lds[FBN * BSTRIDE];
  const int tid = threadIdx.x, lane = tid & 63, wv = tid >> 6;
  const int bid = blockIdx.x;
  const int swz = (bid & 7) * 1024 + (bid >> 3);
  const int bx = swz >> 6, by = swz & 63;
  const int m0 = by * FBM, n0 = bx * FBN;
  const int mA0 = tid >> 2, mA1 = (256 + tid) >> 2;
  const int kcA = tid & 3;
  const int kp0 = kcA ^ swz_s(mA0), kp1 = kcA ^ swz_s(mA1);
  const float* pA0 = A + (size_t)(m0 + mA0) * K_TOT + kcA * 8;
  const float* pA1 = A + (size_t)(m0 + mA1) * K_TOT + kcA * 8;
  __bf16* dA0 = a_lds + mA0 * FBK + kp0 * 8;
  __bf16* dA1 = a_lds + mA1 * FBK + kp1 * 8;
  const int nB = tid & 127, kg = (tid >> 7) * 16;
  const int* pQ = Q + (size_t)kg * N_TOT + n0 + nB;
  __bf16* dB = b_lds + nB * BSTRIDE + kg;
  const int wr = (wv >> 1) * 64, wc = (wv & 1) * 64;
  const int r15 = lane & 15, kgrp = lane >> 4;
  const int selA = kgrp ^ swz_s(r15);
  const __bf16* aRd = a_lds + (wr + r15) * FBK + selA * 8;
  const __bf16* bRd = b_lds + (wc + r15) * BSTRIDE + kgrp * 8;
  f32x4 acc[4][4];
  #pragma unroll
  for (int i = 0; i < 4; ++i)
    #pragma unroll
    for (int j = 0; j < 4; ++j) acc[i][j] = {0.f, 0.f, 0.f, 0.f};
  for (int kt = 0; kt < K_TOT / FBK; ++kt) {
    f32x4 a0lo = *(const f32x4*)(pA0), a0hi = *(const f32x4*)(pA0 + 4);
    f32x4 a1lo = *(const f32x4*)(pA1), a1hi = *(const f32x4*)(pA1 + 4);
    pA0 += FBK; pA1 += FBK;
    bf16x8 a0, a1;
    #pragma unroll
    for (int i = 0; i < 4; ++i) {
      a0[i] = (__bf16)a0lo[i]; a0[i + 4] = (__bf16)a0hi[i];
      a1[i] = (__bf16)a1lo[i]; a1[i + 4] = (__bf16)a1hi[i];
    }
    int qv[16];
    #pragma unroll
    for (int i = 0; i < 16; ++i) qv[i] = pQ[(size_t)i * N_TOT];
    pQ += (size_t)FBK * N_TOT;
    bf16x8 v0, v1;
    #pragma unroll
    for (int i = 0; i < 8; ++i) { v0[i] = (__bf16)(float)qv[i]; v1[i] = (__bf16)(float)qv[i + 8]; }
    *(bf16x8*)dA0 = a0; *(bf16x8*)dA1 = a1;
    *(bf16x8*)(dB) = v0; *(bf16x8*)(dB + 8) = v1;
    __syncthreads();
    bf16x8 af[4], bfr[4];
    #pragma unroll
    for (int mi = 0; mi < 4; ++mi) af[mi] = *(const bf16x8*)(aRd + mi * 16 * FBK);
    #pragma unroll
    for (int ni = 0; ni < 4; ++ni) bfr[ni] = *(const bf16x8*)(bRd + ni * 16 * BSTRIDE);
    #pragma unroll
    for (int mi = 0; mi < 4; ++mi)
      #pragma unroll
      for (int ni = 0; ni < 4; ++ni)
        acc[mi][ni] = __builtin_amdgcn_mfma_f32_16x16x32_bf16(af[mi], bfr[ni], acc[mi][ni], 0, 0, 0);
    __syncthreads();
  }
  const int colb = n0 + wc + r15, rowb = m0 + wr + kgrp * 4;
  #pragma unroll
  for (int ni = 0; ni < 4; ++ni) {
    const int col = colb + ni * 16;
    const float sc = S[col], bb = Bias[col];
    #pragma unroll
    for (int mi = 0; mi < 4; ++mi) {
      const int row = rowb + mi * 16;
      f32x4 a = acc[mi][ni];
      #pragma unroll
      for (int j = 0; j < 4; ++j)
        O[(size_t)(row + j) * N_TOT + col] = a[j] * sc + bb;
    }
  }
}

extern "C" void kernel_launch(void* const* d_in, const int* in_sizes, int n_in,
                              void* d_out, int out_size, void* d_ws, size_t ws_size,
                              hipStream_t stream) {
  const float* A    = (const float*)d_in[0];
  const int*   Q    = (const int*)d_in[1];
  const float* S    = (const float*)d_in[2];
  const float* Bias = (const float*)d_in[3];
  float*       O    = (float*)d_out;

  const size_t A_BYTES = (size_t)M_TOT * K_TOT * 2;   // 64 MiB
  const size_t B_BYTES = (size_t)N_TOT * K_TOT * 2;   // 128 MiB
  const int    LDS_BYTES = 5 * SLOT_ELEMS * 2;        // 163840 (A:3 + B:2)

  if (ws_size >= A_BYTES + B_BYTES) {
    (void)hipFuncSetAttribute((const void*)&w8a16_gemm_ws<1>,
                              hipFuncAttributeMaxDynamicSharedMemorySize,
                              LDS_BYTES);
    (void)hipFuncSetAttribute((const void*)&w8a16_gemm_ws<0>,
                              hipFuncAttributeMaxDynamicSharedMemorySize,
                              LDS_BYTES);
    __bf16* Abf = (__bf16*)d_ws;
    __bf16* Bt  = (__bf16*)((char*)d_ws + A_BYTES);
    cvt_a_kernel<<<dim3(16384), dim3(256), 0, stream>>>(A, Abf);
    transpose_q_kernel<<<dim3(16384), dim3(256), 0, stream>>>(Q, Bt);
    // A/B split: V1 staggered on by 0..15, V0 control (rot=0) on by 16..31.
    w8a16_gemm_ws<1><<<dim3(1024), dim3(512), LDS_BYTES, stream>>>(
        Abf, Bt, S, Bias, O, 0);
    w8a16_gemm_ws<0><<<dim3(1024), dim3(512), LDS_BYTES, stream>>>(
        Abf, Bt, S, Bias, O, 16);
  } else {
    w8a16_gemm_fused<<<dim3(8192), dim3(256), 0, stream>>>(A, Q, S, Bias, O);
  }
}